// Round 9
// baseline (1182.603 us; speedup 1.0000x reference)
//
#include <hip/hip_runtime.h>
#include <math.h>

// Problem constants (fixed by setup_inputs: B=8, n=256, s=256)
#define NCTRL 256          // control points
#define NA    259          // n + 3 (TPS system size)
#define NAUG  261          // + 2 rhs columns
#define APITCH 264         // padded row pitch (floats) for the augmented matrix
#define BATCH 8
#define SGRID 256
#define NB    32           // LU panel width
#define NPAN  9            // 8 full panels + 1 of width 3
#define PPITCH 36          // LDS row pitch: 36*4=144B, 16B-aligned rows
#define SPITCH 232         // laswp/U12 stage pitch (>= max trailing cols 229)
#define NT    512          // solve block threads (8 waves)
#define PY    4            // eval pixels per thread

// ---------------------------------------------------------------------------
// Ministep engine (r6/r7-proven). Thread tid owns row tid in rr[]; ONE
// barrier per ministep; parity double-buffered publish. NW = waves in block.
// ---------------------------------------------------------------------------
template<int NBC, int NW>
__device__ __forceinline__ void panel_ministeps(
    float (&rr)[NBC], int& org, const int rows,
    const int tid, const int lane, const int wid,
    float (*redrow)[NW][PPITCH], float (*jrow)[PPITCH],
    float (*redv)[NW], int (*redi)[NW], int (*redo_)[NW], int* jorg)
{
  #pragma unroll
  for (int j = 0; j < NBC; ++j){
    const int par = j & 1;
    float bv = (tid >= j && tid < rows) ? fabsf(rr[j]) : -1.0f;
    int bi = tid;
    #pragma unroll
    for (int off = 32; off; off >>= 1){
      float ov = __shfl_xor(bv, off);
      int   oi = __shfl_xor(bi, off);
      if (ov > bv || (ov == bv && oi < bi)){ bv = ov; bi = oi; }
    }
    if (tid == bi){
      redv[par][wid] = bv; redi[par][wid] = bi; redo_[par][wid] = org;
      if (bv >= 0.0f){
        if (NBC == NB){
          #pragma unroll
          for (int q = 0; q < 8; ++q){
            float4 v; v.x=rr[4*q]; v.y=rr[4*q+1]; v.z=rr[4*q+2]; v.w=rr[4*q+3];
            *(float4*)&redrow[par][wid][4*q] = v;
          }
        } else {
          #pragma unroll
          for (int c = 0; c < NBC; ++c) redrow[par][wid][c] = rr[c];
        }
      }
    }
    if (tid == j){
      jorg[par] = org;
      if (NBC == NB){
        #pragma unroll
        for (int q = 0; q < 8; ++q){
          float4 v; v.x=rr[4*q]; v.y=rr[4*q+1]; v.z=rr[4*q+2]; v.w=rr[4*q+3];
          *(float4*)&jrow[par][4*q] = v;
        }
      } else {
        #pragma unroll
        for (int c = 0; c < NBC; ++c) jrow[par][c] = rr[c];
      }
    }
    __syncthreads();
    float gv = redv[par][0]; int gw = 0;
    #pragma unroll
    for (int w = 1; w < NW; ++w){
      if (redv[par][w] > gv ||
          (redv[par][w] == gv && redi[par][w] < redi[par][gw])){
        gv = redv[par][w]; gw = w;
      }
    }
    const int gbi  = redi[par][gw];
    const int gorg = redo_[par][gw];
    float pr[NBC];
    if (NBC == NB){
      #pragma unroll
      for (int q = 0; q < 8; ++q){
        float4 v = *(const float4*)&redrow[par][gw][4*q];
        pr[4*q]=v.x; pr[4*q+1]=v.y; pr[4*q+2]=v.z; pr[4*q+3]=v.w;
      }
    } else {
      #pragma unroll
      for (int c = 0; c < NBC; ++c) pr[c] = redrow[par][gw][c];
    }
    if (gbi != j){
      if (tid == j){
        #pragma unroll
        for (int c = 0; c < NBC; ++c) rr[c] = pr[c];
        org = gorg;
      } else if (tid == gbi){
        #pragma unroll
        for (int c = 0; c < NBC; ++c) rr[c] = jrow[par][c];
        org = jorg[par];
      }
    }
    if (tid > j && tid < rows){
      const float rpiv = 1.0f / pr[j];
      float f = rr[j] * rpiv;
      rr[j] = f;
      #pragma unroll
      for (int c = j+1; c < NBC; ++c) rr[c] = fmaf(-f, pr[c], rr[c]);
    }
  }
}

// ---------------------------------------------------------------------------
// ONE kernel per batch: build -> 9x(panel + laswp + TRSM + GEMM) -> backsub.
// 8 blocks x 512 threads; each batch stays on one CU / one XCD L2. All sync
// is block-internal __syncthreads — no grid sync, no cross-XCD traffic.
// ---------------------------------------------------------------------------
__global__ __launch_bounds__(NT, 2) void solve_all(const float* __restrict__ src,
                                                   const float* __restrict__ dst,
                                                   float* __restrict__ A,
                                                   float* __restrict__ wv){
  const int b = blockIdx.x;
  float* Ab = A + (size_t)b*NA*APITCH;
  const int tid  = threadIdx.x;
  const int lane = tid & 63;
  const int wid  = tid >> 6;

  __shared__ float pan[NA][PPITCH];       // 37.3 KB — factored panel (L\U)
  __shared__ float stg[2*NB][SPITCH];     // 59.4 KB — laswp stage / U12
  __shared__ float redrow[2][8][PPITCH];  //  2.3 KB
  __shared__ float jrowS[2][PPITCH];
  __shared__ float redv[2][8];
  __shared__ int   redi[2][8], redo_[2][8], jorg[2];
  __shared__ int   perm[NA], mvlist[2*NB], mvcnt;
  __shared__ float sx[NCTRL], sy[NCTRL];
  __shared__ float t2[NA][2], xs[NA][2];
  __shared__ float u11[NB][NB+1];

  // ===================== phase 0: build this batch's system =====================
  if (tid < NCTRL){
    float2 v = ((const float2*)(src + b*NCTRL*2))[tid];
    sx[tid] = v.x; sy[tid] = v.y;
  }
  __syncthreads();
  {
    const float* db = dst + b*NCTRL*2;
    for (int idx = tid; idx < NA*APITCH; idx += NT){
      int r = idx / APITCH;
      int c = idx - r*APITCH;
      float v = 0.0f;
      if (r < NCTRL){
        if (c < NCTRL){
          float dx = sx[r] - sx[c];
          float dy = sy[r] - sy[c];
          v = __builtin_amdgcn_sqrtf(fmaf(dx, dx, dy*dy));
        } else if (c == NCTRL)   v = 1.0f;
        else if (c == NCTRL+1)   v = sx[r];
        else if (c == NCTRL+2)   v = sy[r];
        else if (c == NA)        v = db[2*r];
        else if (c == NA+1)      v = db[2*r+1];
      } else if (c < NCTRL){
        v = (r == NCTRL) ? 1.0f : ((r == NCTRL+1) ? sx[c] : sy[c]);
      }
      Ab[idx] = v;
    }
  }
  __syncthreads();

  // ===================== phases 1..8: full-width panels =====================
  for (int p = 0; p < NPAN-1; ++p){
    const int k0   = p*NB;
    const int rows = NA - k0;
    const int ctop = k0 + NB;
    const int tc   = NAUG - ctop;        // includes 2 rhs cols

    // ---- stage panel (coalesced float4) ----
    for (int idx = tid; idx < rows*8; idx += NT){
      int i = idx >> 3, q = idx & 7;
      *(float4*)&pan[i][4*q] =
        *(const float4*)(Ab + (size_t)(k0+i)*APITCH + k0 + 4*q);
    }
    if (tid == 0) mvcnt = 0;
    __syncthreads();

    // ---- register panel factorization (1 barrier / ministep) ----
    {
      float rr[NB];
      int org = tid;
      if (tid < rows){
        #pragma unroll
        for (int q = 0; q < 8; ++q){
          float4 v = *(const float4*)&pan[tid][4*q];
          rr[4*q]=v.x; rr[4*q+1]=v.y; rr[4*q+2]=v.z; rr[4*q+3]=v.w;
        }
      } else {
        #pragma unroll
        for (int c = 0; c < NB; ++c) rr[c] = 0.0f;
      }
      panel_ministeps<NB,8>(rr, org, rows, tid, lane, wid,
                            redrow, jrowS, redv, redi, redo_, jorg);
      if (tid < rows){
        #pragma unroll
        for (int q = 0; q < 8; ++q){
          float4 v; v.x=rr[4*q]; v.y=rr[4*q+1]; v.z=rr[4*q+2]; v.w=rr[4*q+3];
          *(float4*)&pan[tid][4*q] = v;
        }
        perm[tid] = org;
      }
    }
    __syncthreads();

    // ---- U11 write-back (backsub needs it) ----
    for (int idx = tid; idx < NB*NB; idx += NT){
      int r = idx >> 5, c = idx & 31;
      Ab[(size_t)(k0+r)*APITCH + k0 + c] = pan[r][c];
    }
    // ---- moved-row list ----
    for (int i = tid; i < rows; i += NT)
      if (perm[i] != i){ int s = atomicAdd(&mvcnt, 1); mvlist[s] = i; }
    __syncthreads();

    // ---- laswp: physically permute trailing cols of moved rows ----
    const int M = mvcnt;                 // <= 64
    if (M > 0){
      for (int idx = tid; idx < M*tc; idx += NT){
        int m = idx / tc, c = idx - m*tc;
        stg[m][c] = Ab[(size_t)(k0 + perm[mvlist[m]])*APITCH + ctop + c];
      }
      __syncthreads();
      for (int idx = tid; idx < M*tc; idx += NT){
        int m = idx / tc, c = idx - m*tc;
        Ab[(size_t)(k0 + mvlist[m])*APITCH + ctop + c] = stg[m][c];
      }
      __syncthreads();
    }

    // ---- TRSM: U12 = L11^{-1} A12 (incl rhs), thread-per-column ----
    for (int c = tid; c < tc; c += NT){
      float u[NB];
      #pragma unroll
      for (int m = 0; m < NB; ++m) u[m] = Ab[(size_t)(k0+m)*APITCH + ctop + c];
      #pragma unroll
      for (int m = 0; m < NB; ++m){
        #pragma unroll
        for (int jj = m+1; jj < NB; ++jj)
          u[jj] = fmaf(-pan[jj][m], u[m], u[jj]);
      }
      #pragma unroll
      for (int m = 0; m < NB; ++m){
        Ab[(size_t)(k0+m)*APITCH + ctop + c] = u[m];
        stg[m][c] = u[m];
      }
    }
    __syncthreads();

    // ---- GEMM: A22 -= L21 * U12 (4x4 register tiles) ----
    const int R = rows - NB;
    if (R > 0){
      const int rt = (R + 3) >> 2, ct = (tc + 3) >> 2;
      for (int t = tid; t < rt*ct; t += NT){
        int tr = t / ct, tcc = t - tr*ct;
        int i0 = tr*4, c0 = tcc*4;
        const bool full = (c0 + 4 <= tc);
        int ir[4];
        #pragma unroll
        for (int r = 0; r < 4; ++r){
          int i = i0 + r;
          ir[r] = (i < R) ? i : (R - 1);
        }
        float acc[4][4];
        #pragma unroll
        for (int r = 0; r < 4; ++r){
          const float* g = Ab + (size_t)(k0 + NB + ir[r])*APITCH + ctop + c0;
          bool rowok = (i0 + r < R);
          if (rowok && full){
            float4 v = *(const float4*)g;
            acc[r][0]=v.x; acc[r][1]=v.y; acc[r][2]=v.z; acc[r][3]=v.w;
          } else {
            #pragma unroll
            for (int c = 0; c < 4; ++c)
              acc[r][c] = (rowok && (c0 + c < tc)) ? g[c] : 0.0f;
          }
        }
        #pragma unroll
        for (int mq = 0; mq < NB/4; ++mq){
          float4 lv[4];
          #pragma unroll
          for (int r = 0; r < 4; ++r)
            lv[r] = *(const float4*)&pan[NB + ir[r]][4*mq];
          #pragma unroll
          for (int mi = 0; mi < 4; ++mi){
            float4 uv = *(const float4*)&stg[4*mq + mi][c0];
            #pragma unroll
            for (int r = 0; r < 4; ++r){
              float l = (mi==0) ? lv[r].x : (mi==1) ? lv[r].y : (mi==2) ? lv[r].z : lv[r].w;
              acc[r][0] = fmaf(-l, uv.x, acc[r][0]);
              acc[r][1] = fmaf(-l, uv.y, acc[r][1]);
              acc[r][2] = fmaf(-l, uv.z, acc[r][2]);
              acc[r][3] = fmaf(-l, uv.w, acc[r][3]);
            }
          }
        }
        #pragma unroll
        for (int r = 0; r < 4; ++r){
          if (i0 + r < R){
            float* g = Ab + (size_t)(k0 + NB + i0 + r)*APITCH + ctop + c0;
            if (full){
              float4 v; v.x=acc[r][0]; v.y=acc[r][1]; v.z=acc[r][2]; v.w=acc[r][3];
              *(float4*)g = v;
            } else {
              #pragma unroll
              for (int c = 0; c < 4; ++c)
                if (c0 + c < tc) g[c] = acc[r][c];
            }
          }
        }
      }
    }
    __syncthreads();
  }

  // ===================== phase 9: 3x3 tail panel =====================
  {
    const int k0 = (NPAN-1)*NB;          // 256
    const int rows = 3, tc = 2;
    for (int idx = tid; idx < rows*3; idx += NT){
      int i = idx / 3, c = idx - i*3;
      pan[i][c] = Ab[(size_t)(k0+i)*APITCH + k0 + c];
    }
    if (tid == 0) mvcnt = 0;
    __syncthreads();
    {
      float rr[3];
      int org = tid;
      if (tid < rows){
        #pragma unroll
        for (int c = 0; c < 3; ++c) rr[c] = pan[tid][c];
      } else {
        #pragma unroll
        for (int c = 0; c < 3; ++c) rr[c] = 0.0f;
      }
      panel_ministeps<3,8>(rr, org, rows, tid, lane, wid,
                           redrow, jrowS, redv, redi, redo_, jorg);
      if (tid < rows){
        #pragma unroll
        for (int c = 0; c < 3; ++c) pan[tid][c] = rr[c];
        perm[tid] = org;
      }
    }
    __syncthreads();
    if (tid < 9){
      int r = tid / 3, c = tid - r*3;
      Ab[(size_t)(k0+r)*APITCH + k0 + c] = pan[r][c];
    }
    for (int i = tid; i < rows; i += NT)
      if (perm[i] != i){ int s = atomicAdd(&mvcnt, 1); mvlist[s] = i; }
    __syncthreads();
    const int M = mvcnt;
    if (M > 0){
      if (tid < M*tc){
        int m = tid / tc, c = tid - m*tc;
        stg[m][c] = Ab[(size_t)(k0 + perm[mvlist[m]])*APITCH + NA + c];
      }
      __syncthreads();
      if (tid < M*tc){
        int m = tid / tc, c = tid - m*tc;
        Ab[(size_t)(k0 + mvlist[m])*APITCH + NA + c] = stg[m][c];
      }
      __syncthreads();
    }
    if (tid < tc){                       // forward-solve rhs vs L33
      float u0 = Ab[(size_t)(k0+0)*APITCH + NA + tid];
      float u1 = Ab[(size_t)(k0+1)*APITCH + NA + tid];
      float u2 = Ab[(size_t)(k0+2)*APITCH + NA + tid];
      u1 = fmaf(-pan[1][0], u0, u1);
      u2 = fmaf(-pan[2][0], u0, u2);
      u2 = fmaf(-pan[2][1], u1, u2);
      Ab[(size_t)(k0+0)*APITCH + NA + tid] = u0;
      Ab[(size_t)(k0+1)*APITCH + NA + tid] = u1;
      Ab[(size_t)(k0+2)*APITCH + NA + tid] = u2;
    }
    __syncthreads();
  }

  // ===================== phase 10: back-substitution =====================
  for (int i = tid; i < NA; i += NT){
    t2[i][0] = Ab[(size_t)i*APITCH + NA];
    t2[i][1] = Ab[(size_t)i*APITCH + NA + 1];
  }
  __syncthreads();
  for (int bp = NPAN-1; bp >= 0; --bp){
    const int k0 = bp*NB;
    const int nb = (NA - k0 < NB) ? (NA - k0) : NB;
    for (int idx = tid; idx < nb*nb; idx += NT){
      int r = idx / nb, c = idx - r*nb;
      u11[r][c] = Ab[(size_t)(k0+r)*APITCH + k0 + c];
    }
    __syncthreads();
    if (wid == 0){
      int j = lane >> 1, ch = lane & 1;
      float tval = (j < nb) ? t2[k0+j][ch] : 0.0f;
      for (int k = nb-1; k >= 0; --k){
        float tk = __shfl(tval, 2*k + ch);
        float xk = tk / u11[k][k];
        if (j <  k) tval = fmaf(-u11[j][k], xk, tval);
        if (j == k) tval = xk;
      }
      if (j < nb) xs[k0+j][ch] = tval;
    }
    __syncthreads();
    if (nb == NB){
      const int q = tid & 7;
      for (int base = 0; base < k0; base += 64){   // 512/8 rows per pass
        const int i = base + (tid >> 3);
        float px = 0.0f, py = 0.0f;
        if (i < k0){
          float4 v = *(const float4*)(Ab + (size_t)i*APITCH + k0 + 4*q);
          px = v.x*xs[k0+4*q+0][0] + v.y*xs[k0+4*q+1][0]
             + v.z*xs[k0+4*q+2][0] + v.w*xs[k0+4*q+3][0];
          py = v.x*xs[k0+4*q+0][1] + v.y*xs[k0+4*q+1][1]
             + v.z*xs[k0+4*q+2][1] + v.w*xs[k0+4*q+3][1];
        }
        px += __shfl_xor(px, 1); px += __shfl_xor(px, 2); px += __shfl_xor(px, 4);
        py += __shfl_xor(py, 1); py += __shfl_xor(py, 2); py += __shfl_xor(py, 4);
        if (q == 0 && i < k0){
          t2[i][0] -= px;
          t2[i][1] -= py;
        }
      }
    } else {
      for (int i = tid; i < k0; i += NT){
        float s0 = 0.0f, s1 = 0.0f;
        #pragma unroll
        for (int m = 0; m < 3; ++m){
          float u = Ab[(size_t)i*APITCH + k0 + m];
          s0 = fmaf(u, xs[k0+m][0], s0);
          s1 = fmaf(u, xs[k0+m][1], s1);
        }
        t2[i][0] -= s0;
        t2[i][1] -= s1;
      }
    }
    __syncthreads();
  }
  for (int i = tid; i < NA; i += NT){
    wv[((size_t)b*NA + i)*2 + 0] = xs[i][0];
    wv[((size_t)b*NA + i)*2 + 1] = xs[i][1];
  }
}

// ---------------------------------------------------------------------------
// Kernel 2: evaluate the warp. PY pixels (same column) per thread: dx^2
// hoisted, one ds_read_b128 per ctrl point, raw v_sqrt_f32.
// ---------------------------------------------------------------------------
__global__ __launch_bounds__(256) void eval_kernel(const float* __restrict__ src,
                                                   const float* __restrict__ wv,
                                                   float* __restrict__ out){
  const int b  = blockIdx.x >> 6;          // 8 batches x 64 y-groups
  const int yg = blockIdx.x & 63;
  const int xi = threadIdx.x;
  __shared__ float4 cw[NCTRL];             // (sx, sy, wx, wy)
  const float* sb = src + b*NCTRL*2;
  const float* wb = wv + (size_t)b*NA*2;
  {
    float2 sv = ((const float2*)sb)[xi];
    float2 wv2 = ((const float2*)wb)[xi];
    cw[xi] = make_float4(sv.x, sv.y, wv2.x, wv2.y);
  }
  __syncthreads();

  const float step = 2.0f/255.0f;
  const float gx = -1.0f + step*(float)xi;
  const float w0x = wb[512], w1x = wb[514], w2x = wb[516];
  const float w0y = wb[513], w1y = wb[515], w2y = wb[517];

  float gy[PY], ax[PY], ay[PY];
  #pragma unroll
  for (int p = 0; p < PY; ++p){
    gy[p] = -1.0f + step*(float)(yg*PY + p);
    ax[p] = w0x + w1x*gx + w2x*gy[p];
    ay[p] = w0y + w1y*gx + w2y*gy[p];
  }

  #pragma unroll 4
  for (int j = 0; j < NCTRL; ++j){
    float4 c = cw[j];
    float dx = gx - c.x;
    float dx2 = dx*dx;
    #pragma unroll
    for (int p = 0; p < PY; ++p){
      float dy = gy[p] - c.y;
      float r = __builtin_amdgcn_sqrtf(fmaf(dy, dy, dx2));
      ax[p] = fmaf(r, c.z, ax[p]);
      ay[p] = fmaf(r, c.w, ay[p]);
    }
  }

  const int y0 = yg*PY;
  #pragma unroll
  for (int p = 0; p < PY; ++p){
    out[((size_t)(b*2    )*SGRID + y0 + p)*SGRID + xi] = ax[p];
    out[((size_t)(b*2 + 1)*SGRID + y0 + p)*SGRID + xi] = ay[p];
  }
}

// ---------------------------------------------------------------------------
extern "C" void kernel_launch(void* const* d_in, const int* in_sizes, int n_in,
                              void* d_out, int out_size, void* d_ws, size_t ws_size,
                              hipStream_t stream) {
  const float* src = (const float*)d_in[0];
  const float* dst = (const float*)d_in[1];
  float* out = (float*)d_out;

  const size_t matElems = (size_t)BATCH*NA*APITCH;
  float* A  = (float*)d_ws;
  float* wv = A + matElems;

  solve_all<<<BATCH, NT, 0, stream>>>(src, dst, A, wv);
  eval_kernel<<<BATCH*(SGRID/PY), 256, 0, stream>>>(src, wv, out);
}

// Round 10
// 677.635 us; speedup vs baseline: 1.7452x; 1.7452x over previous
//
#include <hip/hip_runtime.h>
#include <math.h>

// Problem constants (fixed by setup_inputs: B=8, n=256, s=256)
#define NCTRL 256          // control points
#define NA    259          // n + 3 (TPS system size)
#define NAUG  261          // + 2 rhs columns
#define APITCH 264         // padded row pitch (floats) for the augmented matrix
#define BATCH 8
#define SGRID 256
#define NB    32           // LU panel width
#define NPAN  9            // 8 full panels + 1 of width 3
#define PPITCH 36          // LDS row pitch: 36*4=144B, 16B-aligned rows
#define PY    4            // eval pixels per thread

// ---------------------------------------------------------------------------
// LDS ministep engine, dynamic-j (small I-footprint). Thread tid owns LDS row
// rowbase[tid]. ONE barrier per ministep. Per-wave argmax winners publish
// their full row + (val,idx,org) BEFORE the barrier (parity double-buffered);
// after it, everyone scans NW candidates, the displaced rows adopt content,
// and all rows > j update against the PUBLISHED pivot row (never rowbase[j],
// which is being rewritten). In-thread LDS ordering covers own-row reuse.
// ---------------------------------------------------------------------------
template<int NW>
__device__ __forceinline__ void panel_lds_engine(
    float (*rowbase)[PPITCH], const int rows, const int nb, int& org,
    const int tid, const int lane, const int wid,
    float (*redrow)[NW][PPITCH], float (*jrow)[PPITCH],
    float (*redv)[NW], int (*redi)[NW], int (*redo_)[NW], int* jorg)
{
  for (int j = 0; j < nb; ++j){
    const int par = j & 1;
    // per-wave argmax over own-row column j
    float bv = (tid >= j && tid < rows) ? fabsf(rowbase[tid][j]) : -1.0f;
    int bi = tid;
    #pragma unroll
    for (int off = 32; off; off >>= 1){
      float ov = __shfl_xor(bv, off);
      int   oi = __shfl_xor(bi, off);
      if (ov > bv || (ov == bv && oi < bi)){ bv = ov; bi = oi; }
    }
    if (tid == bi){                       // wave winner publishes
      redv[par][wid] = bv; redi[par][wid] = bi; redo_[par][wid] = org;
      #pragma unroll
      for (int q = 0; q < 8; ++q)
        *(float4*)&redrow[par][wid][4*q] = *(const float4*)&rowbase[tid][4*q];
    }
    if (tid == j){                        // displaced row publishes
      jorg[par] = org;
      #pragma unroll
      for (int q = 0; q < 8; ++q)
        *(float4*)&jrow[par][4*q] = *(const float4*)&rowbase[tid][4*q];
    }
    __syncthreads();
    // global winner among NW wave candidates
    float gv = redv[par][0]; int gw = 0;
    #pragma unroll
    for (int w = 1; w < NW; ++w){
      if (redv[par][w] > gv ||
          (redv[par][w] == gv && redi[par][w] < redi[par][gw])){
        gv = redv[par][w]; gw = w;
      }
    }
    const int gbi = redi[par][gw];
    const float* pvrow = redrow[par][gw];
    // physical swap via adopt (only rows j and gbi write; others untouched)
    if (gbi != j){
      if (tid == j){
        #pragma unroll
        for (int q = 0; q < 8; ++q)
          *(float4*)&rowbase[j][4*q] = *(const float4*)&pvrow[4*q];
        org = redo_[par][gw];
      } else if (tid == gbi){
        #pragma unroll
        for (int q = 0; q < 8; ++q)
          *(float4*)&rowbase[gbi][4*q] = *(const float4*)&jrow[par][4*q];
        org = jorg[par];
      }
    }
    // rank-1 update vs the published pivot row
    if (tid > j && tid < rows){
      const float piv = pvrow[j];
      float f = rowbase[tid][j] / piv;
      rowbase[tid][j] = f;
      const int q0 = (j+1) >> 2;
      {  // boundary quad (partial mask)
        float4 a = *(float4*)&rowbase[tid][4*q0];
        float4 pv = *(const float4*)&pvrow[4*q0];
        if (4*q0+0 > j) a.x = fmaf(-f, pv.x, a.x);
        if (4*q0+1 > j) a.y = fmaf(-f, pv.y, a.y);
        if (4*q0+2 > j) a.z = fmaf(-f, pv.z, a.z);
        if (4*q0+3 > j) a.w = fmaf(-f, pv.w, a.w);
        *(float4*)&rowbase[tid][4*q0] = a;
      }
      for (int q = q0+1; q < 8; ++q){
        float4 a = *(float4*)&rowbase[tid][4*q];
        float4 pv = *(const float4*)&pvrow[4*q];
        a.x = fmaf(-f, pv.x, a.x); a.y = fmaf(-f, pv.y, a.y);
        a.z = fmaf(-f, pv.z, a.z); a.w = fmaf(-f, pv.w, a.w);
        *(float4*)&rowbase[tid][4*q] = a;
      }
    }
  }
}

// ---------------------------------------------------------------------------
// Kernel 1: build this batch's system + factor panel 0. 8 blocks x 320 thr.
// Panel cols (c<32) are mirrored into LDS during build — no global re-read.
// ---------------------------------------------------------------------------
__global__ __launch_bounds__(320) void build_panel0(const float* __restrict__ src,
                                                    const float* __restrict__ dst,
                                                    float* __restrict__ A,
                                                    int* __restrict__ permbuf){
  const int b = blockIdx.x;
  float* Ab = A + (size_t)b*NA*APITCH;
  const int tid  = threadIdx.x;
  const int lane = tid & 63;
  const int wid  = tid >> 6;             // 0..4

  __shared__ float pan[NA][PPITCH];
  __shared__ float redrow[2][5][PPITCH];
  __shared__ float jrow[2][PPITCH];
  __shared__ float redv[2][5];
  __shared__ int   redi[2][5], redo_[2][5], jorg[2];
  __shared__ float sx[NCTRL], sy[NCTRL];

  if (tid < NCTRL){
    float2 v = ((const float2*)(src + b*NCTRL*2))[tid];
    sx[tid] = v.x; sy[tid] = v.y;
  }
  __syncthreads();
  {
    const float* db = dst + b*NCTRL*2;
    for (int idx = tid; idx < NA*APITCH; idx += 320){
      int r = idx / APITCH;
      int c = idx - r*APITCH;
      float v = 0.0f;
      if (r < NCTRL){
        if (c < NCTRL){
          float dx = sx[r] - sx[c];
          float dy = sy[r] - sy[c];
          v = __builtin_amdgcn_sqrtf(fmaf(dx, dx, dy*dy));
        } else if (c == NCTRL)   v = 1.0f;
        else if (c == NCTRL+1)   v = sx[r];
        else if (c == NCTRL+2)   v = sy[r];
        else if (c == NA)        v = db[2*r];
        else if (c == NA+1)      v = db[2*r+1];
      } else if (c < NCTRL){
        v = (r == NCTRL) ? 1.0f : ((r == NCTRL+1) ? sx[c] : sy[c]);
      }
      Ab[idx] = v;
      if (c < NB) pan[r][c] = v;         // mirror panel-0 columns into LDS
    }
  }
  __syncthreads();

  int org = tid;
  panel_lds_engine<5>(pan, NA, NB, org, tid, lane, wid,
                      redrow, jrow, redv, redi, redo_, jorg);

  if (tid < NA) permbuf[b*(NPAN*NA) + tid] = org;
  __syncthreads();
  for (int idx = tid; idx < NA*8; idx += 320){
    int i = idx >> 3, q = idx & 7;
    *(float4*)(Ab + (size_t)i*APITCH + 4*q) = *(const float4*)&pan[i][4*q];
  }
}

// ---------------------------------------------------------------------------
// Kernel 2: trailing update for panel p, one block per 32-col strip.
// laswp gather -> TRSM -> GEMM; strip 0 also factorizes the NEXT panel from
// its LDS strip (LDS engine) and writes panel(+rhs for the 3-wide tail)+perm.
// ---------------------------------------------------------------------------
template<bool LOOK>
__global__ __launch_bounds__(256) void update_kernel(float* __restrict__ A,
                                                     int* __restrict__ permbuf,
                                                     int k0, int pidx, int sb,
                                                     int nbn, int wbw){
  const int rows = NA - k0;
  const int ctop = k0 + NB;
  const int tc   = NAUG - ctop;
  const int b    = blockIdx.x / sb;
  const int s    = blockIdx.x - b*sb;
  const int c0   = s*32;
  const int W    = (tc - c0 < 32) ? (tc - c0) : 32;
  float* Ab = A + (size_t)b*NA*APITCH;
  const int tid  = threadIdx.x;
  const int lane = tid & 63;
  const int wid  = tid >> 6;             // 0..3

  __shared__ float pan[NA][PPITCH];      // factored panel (L\U)
  __shared__ float stage[NA][PPITCH];    // permuted strip / next panel
  __shared__ float ustg[NB][PPITCH];     // U12 strip
  __shared__ int   perm[NA];
  __shared__ float redrow[2][4][PPITCH];
  __shared__ float jrow[2][PPITCH];
  __shared__ float redv[2][4];
  __shared__ int   redi[2][4], redo_[2][4], jorg[2];

  for (int i = tid; i < rows; i += 256)
    perm[i] = permbuf[b*(NPAN*NA) + pidx*NA + i];
  for (int idx = tid; idx < rows*8; idx += 256){
    int i = idx >> 3, q = idx & 7;
    *(float4*)&pan[i][4*q] =
      *(const float4*)(Ab + (size_t)(k0+i)*APITCH + k0 + 4*q);
  }
  __syncthreads();

  // laswp gather: stage[i][c] = A[k0+perm[i]][ctop+c0+c]
  for (int idx = tid; idx < rows*W; idx += 256){
    int i = idx / W, c = idx - i*W;
    stage[i][c] = Ab[(size_t)(k0+perm[i])*APITCH + ctop + c0 + c];
  }
  __syncthreads();

  // TRSM: U12 = L11^{-1} A12, thread-per-column from LDS
  if (tid < W){
    float u[NB];
    #pragma unroll
    for (int m = 0; m < NB; ++m) u[m] = stage[m][tid];
    #pragma unroll
    for (int m = 0; m < NB; ++m){
      #pragma unroll
      for (int jj = m+1; jj < NB; ++jj)
        u[jj] = fmaf(-pan[jj][m], u[m], u[jj]);
    }
    #pragma unroll
    for (int m = 0; m < NB; ++m){
      ustg[m][tid] = u[m];
      Ab[(size_t)(k0+m)*APITCH + ctop + c0 + tid] = u[m];
    }
  }
  __syncthreads();

  // GEMM: A22 -= L21 * U12 (4x4 register tiles)
  const int R = rows - NB;
  if (R > 0){
    const int rt = (R + 3) >> 2, ct = (W + 3) >> 2;
    for (int t = tid; t < rt*ct; t += 256){
      int tr = t / ct, tcc = t - tr*ct;
      int i0 = tr*4, cc0 = tcc*4;
      const bool full = (cc0 + 4 <= W);
      int ir[4];
      #pragma unroll
      for (int r = 0; r < 4; ++r){
        int i = i0 + r;
        ir[r] = (i < R) ? i : (R - 1);
      }
      float acc[4][4];
      #pragma unroll
      for (int r = 0; r < 4; ++r){
        if (full){
          float4 v = *(const float4*)&stage[NB + ir[r]][cc0];
          acc[r][0]=v.x; acc[r][1]=v.y; acc[r][2]=v.z; acc[r][3]=v.w;
        } else {
          #pragma unroll
          for (int c = 0; c < 4; ++c)
            acc[r][c] = (cc0 + c < W) ? stage[NB + ir[r]][cc0 + c] : 0.0f;
        }
      }
      #pragma unroll
      for (int mq = 0; mq < NB/4; ++mq){
        float4 lv[4];
        #pragma unroll
        for (int r = 0; r < 4; ++r)
          lv[r] = *(const float4*)&pan[NB + ir[r]][4*mq];
        #pragma unroll
        for (int mi = 0; mi < 4; ++mi){
          float4 uv = *(const float4*)&ustg[4*mq + mi][cc0];
          #pragma unroll
          for (int r = 0; r < 4; ++r){
            float l = (mi==0) ? lv[r].x : (mi==1) ? lv[r].y : (mi==2) ? lv[r].z : lv[r].w;
            acc[r][0] = fmaf(-l, uv.x, acc[r][0]);
            acc[r][1] = fmaf(-l, uv.y, acc[r][1]);
            acc[r][2] = fmaf(-l, uv.z, acc[r][2]);
            acc[r][3] = fmaf(-l, uv.w, acc[r][3]);
          }
        }
      }
      #pragma unroll
      for (int r = 0; r < 4; ++r){
        if (i0 + r < R){
          float* g = Ab + (size_t)(k0 + NB + i0 + r)*APITCH + ctop + c0 + cc0;
          if (full){
            float4 v; v.x=acc[r][0]; v.y=acc[r][1]; v.z=acc[r][2]; v.w=acc[r][3];
            *(float4*)g = v;
            if (LOOK && s == 0) *(float4*)&stage[NB + i0 + r][cc0] = v;
          } else {
            #pragma unroll
            for (int c = 0; c < 4; ++c)
              if (cc0 + c < W){
                g[c] = acc[r][c];
                if (LOOK && s == 0) stage[NB + i0 + r][cc0 + c] = acc[r][c];
              }
          }
        }
      }
    }
  }

  // lookahead: factor the NEXT panel in LDS (strip 0 only)
  if (LOOK && s == 0){
    __syncthreads();
    const int k0n   = k0 + NB;
    const int rowsN = rows - NB;          // <= 227 < 256 threads
    int org = tid;
    panel_lds_engine<4>(&stage[NB], rowsN, nbn, org, tid, lane, wid,
                        redrow, jrow, redv, redi, redo_, jorg);
    if (tid < rowsN) permbuf[b*(NPAN*NA) + (pidx+1)*NA + tid] = org;
    __syncthreads();
    // write back wbw cols (32 for full panels; 5 = 3 panel + 2 rhs for tail,
    // whose rhs columns were forward-eliminated by the engine's quad updates)
    if (wbw == NB){
      for (int idx = tid; idx < rowsN*8; idx += 256){
        int i = idx >> 3, q = idx & 7;
        *(float4*)(Ab + (size_t)(k0n+i)*APITCH + k0n + 4*q) =
          *(const float4*)&stage[NB + i][4*q];
      }
    } else {
      for (int idx = tid; idx < rowsN*wbw; idx += 256){
        int i = idx / wbw, c = idx - i*wbw;
        Ab[(size_t)(k0n+i)*APITCH + k0n + c] = stage[NB + i][c];
      }
    }
  }
}

// ---------------------------------------------------------------------------
// Kernel 3: back-substitution (r7-proven right-looking version).
// ---------------------------------------------------------------------------
__global__ __launch_bounds__(512) void backsub_kernel(const float* __restrict__ A,
                                                      float* __restrict__ wv){
  const int b = blockIdx.x;
  const float* Ab = A + (size_t)b*NA*APITCH;
  const int tid  = threadIdx.x;
  const int lane = tid & 63;
  const int wid  = tid >> 6;

  __shared__ float t2[NA][2];
  __shared__ float xs[NA][2];
  __shared__ float u11[NB][NB+1];

  for (int i = tid; i < NA; i += 512){
    t2[i][0] = Ab[(size_t)i*APITCH + NA];
    t2[i][1] = Ab[(size_t)i*APITCH + NA + 1];
  }
  __syncthreads();

  for (int bp = NPAN-1; bp >= 0; --bp){
    const int k0 = bp*NB;
    const int nb = (NA - k0 < NB) ? (NA - k0) : NB;

    for (int idx = tid; idx < nb*nb; idx += 512){
      int r = idx / nb, c = idx - r*nb;
      u11[r][c] = Ab[(size_t)(k0+r)*APITCH + k0 + c];
    }
    __syncthreads();

    if (wid == 0){
      int j = lane >> 1, ch = lane & 1;
      float tval = (j < nb) ? t2[k0+j][ch] : 0.0f;
      for (int k = nb-1; k >= 0; --k){
        float tk = __shfl(tval, 2*k + ch);
        float xk = tk / u11[k][k];
        if (j <  k) tval = fmaf(-u11[j][k], xk, tval);
        if (j == k) tval = xk;
      }
      if (j < nb) xs[k0+j][ch] = tval;
    }
    __syncthreads();

    if (nb == NB){
      const int q = tid & 7;
      for (int base = 0; base < k0; base += 64){
        const int i = base + (tid >> 3);
        float px = 0.0f, py = 0.0f;
        if (i < k0){
          float4 v = *(const float4*)(Ab + (size_t)i*APITCH + k0 + 4*q);
          px = v.x*xs[k0+4*q+0][0] + v.y*xs[k0+4*q+1][0]
             + v.z*xs[k0+4*q+2][0] + v.w*xs[k0+4*q+3][0];
          py = v.x*xs[k0+4*q+0][1] + v.y*xs[k0+4*q+1][1]
             + v.z*xs[k0+4*q+2][1] + v.w*xs[k0+4*q+3][1];
        }
        px += __shfl_xor(px, 1); px += __shfl_xor(px, 2); px += __shfl_xor(px, 4);
        py += __shfl_xor(py, 1); py += __shfl_xor(py, 2); py += __shfl_xor(py, 4);
        if (q == 0 && i < k0){
          t2[i][0] -= px;
          t2[i][1] -= py;
        }
      }
    } else {
      for (int i = tid; i < k0; i += 512){
        float s0 = 0.0f, s1 = 0.0f;
        #pragma unroll
        for (int m = 0; m < 3; ++m){
          float u = Ab[(size_t)i*APITCH + k0 + m];
          s0 = fmaf(u, xs[k0+m][0], s0);
          s1 = fmaf(u, xs[k0+m][1], s1);
        }
        t2[i][0] -= s0;
        t2[i][1] -= s1;
      }
    }
    __syncthreads();
  }

  for (int i = tid; i < NA; i += 512){
    wv[((size_t)b*NA + i)*2 + 0] = xs[i][0];
    wv[((size_t)b*NA + i)*2 + 1] = xs[i][1];
  }
}

// ---------------------------------------------------------------------------
// Kernel 4: evaluate the warp. PY pixels (same column) per thread: dx^2
// hoisted, one ds_read_b128 per ctrl point, raw v_sqrt_f32. (r8/r9-proven)
// ---------------------------------------------------------------------------
__global__ __launch_bounds__(256) void eval_kernel(const float* __restrict__ src,
                                                   const float* __restrict__ wv,
                                                   float* __restrict__ out){
  const int b  = blockIdx.x >> 6;          // 8 batches x 64 y-groups
  const int yg = blockIdx.x & 63;
  const int xi = threadIdx.x;
  __shared__ float4 cw[NCTRL];             // (sx, sy, wx, wy)
  const float* sb = src + b*NCTRL*2;
  const float* wb = wv + (size_t)b*NA*2;
  {
    float2 sv = ((const float2*)sb)[xi];
    float2 wv2 = ((const float2*)wb)[xi];
    cw[xi] = make_float4(sv.x, sv.y, wv2.x, wv2.y);
  }
  __syncthreads();

  const float step = 2.0f/255.0f;
  const float gx = -1.0f + step*(float)xi;
  const float w0x = wb[512], w1x = wb[514], w2x = wb[516];
  const float w0y = wb[513], w1y = wb[515], w2y = wb[517];

  float gy[PY], ax[PY], ay[PY];
  #pragma unroll
  for (int p = 0; p < PY; ++p){
    gy[p] = -1.0f + step*(float)(yg*PY + p);
    ax[p] = w0x + w1x*gx + w2x*gy[p];
    ay[p] = w0y + w1y*gx + w2y*gy[p];
  }

  #pragma unroll 4
  for (int j = 0; j < NCTRL; ++j){
    float4 c = cw[j];
    float dx = gx - c.x;
    float dx2 = dx*dx;
    #pragma unroll
    for (int p = 0; p < PY; ++p){
      float dy = gy[p] - c.y;
      float r = __builtin_amdgcn_sqrtf(fmaf(dy, dy, dx2));
      ax[p] = fmaf(r, c.z, ax[p]);
      ay[p] = fmaf(r, c.w, ay[p]);
    }
  }

  const int y0 = yg*PY;
  #pragma unroll
  for (int p = 0; p < PY; ++p){
    out[((size_t)(b*2    )*SGRID + y0 + p)*SGRID + xi] = ax[p];
    out[((size_t)(b*2 + 1)*SGRID + y0 + p)*SGRID + xi] = ay[p];
  }
}

// ---------------------------------------------------------------------------
extern "C" void kernel_launch(void* const* d_in, const int* in_sizes, int n_in,
                              void* d_out, int out_size, void* d_ws, size_t ws_size,
                              hipStream_t stream) {
  const float* src = (const float*)d_in[0];
  const float* dst = (const float*)d_in[1];
  float* out = (float*)d_out;

  const size_t matElems = (size_t)BATCH*NA*APITCH;
  float* A     = (float*)d_ws;
  float* wv    = A + matElems;
  int*   permb = (int*)(wv + (size_t)BATCH*NA*2);

  // build + panel 0
  build_panel0<<<BATCH, 320, 0, stream>>>(src, dst, A, permb);

  // p = 0..6: update + lookahead of panel p+1 (width 32)
  for (int p = 0; p <= 6; ++p){
    const int k0 = p*NB;
    const int tc = NAUG - (k0 + NB);
    const int sb = (tc + 31) >> 5;
    update_kernel<true><<<BATCH*sb, 256, 0, stream>>>(A, permb, k0, p, sb, NB, NB);
  }
  // p = 7: update (1 strip) + lookahead of the 3-wide tail; the engine's quad
  // updates forward-eliminate the 2 rhs columns too, so write back 5 cols.
  update_kernel<true><<<BATCH, 256, 0, stream>>>(A, permb, 7*NB, 7, 1, 3, 5);

  backsub_kernel<<<BATCH, 512, 0, stream>>>(A, wv);
  eval_kernel<<<BATCH*(SGRID/PY), 256, 0, stream>>>(src, wv, out);
}

// Round 11
// 577.837 us; speedup vs baseline: 2.0466x; 1.1727x over previous
//
#include <hip/hip_runtime.h>
#include <math.h>

// Problem constants (fixed by setup_inputs: B=8, n=256, s=256)
#define NCTRL 256          // control points
#define NA    259          // n + 3 (TPS system size)
#define NAUG  261          // + 2 rhs columns
#define APITCH 264         // padded row pitch (floats) for the augmented matrix
#define BATCH 8
#define SGRID 256
#define NB    32           // LU panel width
#define NPAN  9            // 8 full panels + 1 of width 3
#define PPITCH 36          // LDS row pitch: 36*4=144B, 16B-aligned rows
#define PY    4            // eval pixels per thread

// ---------------------------------------------------------------------------
// Flat shift-register panel engine. Thread tid owns row tid in rr[] with
// ALL-STATIC register indexing: each ministep consumes column 0 and shifts.
// Rows never move; winner publishes its row pre-barrier (parity dbuf, proven
// r6 protocol); U row j is captured from the publish buffer; L factors go to
// ftmp by original row; final prefix-scan computes positions and gathers.
// ONE barrier per ministep; ~120-instr dynamic body (I-cache resident).
//   NBC   = register row width (32 full, 8 padded for the 5-wide tail)
//   width = true data width (32, or 5 = 3 panel + 2 rhs)
//   nb    = pivot steps (32, or 3)
// Outputs: panout rows 0..rows-1 = packed L\U in final order; permout[i] =
// original panel-local row at final position i.
// ---------------------------------------------------------------------------
template<int NBC, int NW>
__device__ __forceinline__ void flat_engine(
    float (&rr)[NBC], const int rows, const int nb, const int width,
    const int tid, const int lane, const int wid,
    float (*panout)[PPITCH], float (*ftmp)[PPITCH], int* permout,
    float (*redrow)[NW][PPITCH], float (*redv)[NW], int (*redi)[NW],
    int* scanw)
{
  bool chosen = false;
  int chosenstep = 0;
  for (int j = 0; j < nb; ++j){
    const int par = j & 1;
    const bool active = (tid < rows) && !chosen;
    // wave argmax on current column (= shifted position 0)
    float bv = active ? fabsf(rr[0]) : -1.0f;
    int bi = tid;
    #pragma unroll
    for (int off = 32; off; off >>= 1){
      float ov = __shfl_xor(bv, off);
      int   oi = __shfl_xor(bi, off);
      if (ov > bv || (ov == bv && oi < bi)){ bv = ov; bi = oi; }
    }
    if (tid == bi){                        // per-wave winner publishes
      redv[par][wid] = bv; redi[par][wid] = bi;
      #pragma unroll
      for (int q = 0; q < NBC/4; ++q){
        float4 v; v.x=rr[4*q]; v.y=rr[4*q+1]; v.z=rr[4*q+2]; v.w=rr[4*q+3];
        *(float4*)&redrow[par][wid][4*q] = v;
      }
    }
    __syncthreads();
    // global winner among NW wave candidates
    float gv = redv[par][0]; int gw = 0;
    #pragma unroll
    for (int w = 1; w < NW; ++w){
      if (redv[par][w] > gv ||
          (redv[par][w] == gv && redi[par][w] < redi[par][gw])){
        gv = redv[par][w]; gw = w;
      }
    }
    const int gbi = redi[par][gw];
    // pivot row -> registers (broadcast b128 reads)
    float pr[NBC];
    #pragma unroll
    for (int q = 0; q < NBC/4; ++q){
      float4 v = *(const float4*)&redrow[par][gw][4*q];
      pr[4*q]=v.x; pr[4*q+1]=v.y; pr[4*q+2]=v.z; pr[4*q+3]=v.w;
    }
    // capture U row j (cols j..width-1) from the publish buffer
    if (tid < width - j) panout[j][j + tid] = redrow[par][gw][tid];
    if (tid == gbi){ chosen = true; chosenstep = j; }
    // update + shift, all in registers (static indices)
    if (active && tid != gbi){
      const float rpiv = 1.0f / pr[0];
      const float f = rr[0] * rpiv;
      ftmp[tid][j] = f;                    // L factor by ORIGINAL row
      #pragma unroll
      for (int c = 0; c < NBC-1; ++c)
        rr[c] = fmaf(-f, pr[c+1], rr[c+1]);
    }
  }
  // final positions: chosen -> its step; unchosen -> nb + rank (orig order)
  {
    int x = (tid < rows && !chosen) ? 1 : 0;
    int sPS = x;
    #pragma unroll
    for (int off = 1; off < 64; off <<= 1){
      int o = __shfl_up(sPS, off);
      if (lane >= off) sPS += o;
    }
    if (lane == 63) scanw[wid] = sPS;
    __syncthreads();
    int base = 0;
    for (int w = 0; w < wid; ++w) base += scanw[w];
    if (tid < rows){
      const int newloc = chosen ? chosenstep : (nb + base + sPS - x);
      permout[newloc] = tid;
      const int lim = chosen ? chosenstep : nb;
      for (int c = 0; c < lim; ++c) panout[newloc][c] = ftmp[tid][c];
    }
  }
  __syncthreads();
}

// ---------------------------------------------------------------------------
// Kernel 1: build this batch's system + factor panel 0 (flat engine).
// ---------------------------------------------------------------------------
__global__ __launch_bounds__(320) void build_panel0(const float* __restrict__ src,
                                                    const float* __restrict__ dst,
                                                    float* __restrict__ A,
                                                    int* __restrict__ permbuf){
  const int b = blockIdx.x;
  float* Ab = A + (size_t)b*NA*APITCH;
  const int tid  = threadIdx.x;
  const int lane = tid & 63;
  const int wid  = tid >> 6;             // 0..4

  __shared__ float pan[NA][PPITCH];
  __shared__ float ftmp[NA][PPITCH];
  __shared__ int   perm[NA];
  __shared__ float redrow[2][5][PPITCH];
  __shared__ float redv[2][5];
  __shared__ int   redi[2][5], scanw[5];
  __shared__ float sx[NCTRL], sy[NCTRL];

  if (tid < NCTRL){
    float2 v = ((const float2*)(src + b*NCTRL*2))[tid];
    sx[tid] = v.x; sy[tid] = v.y;
  }
  __syncthreads();
  {
    const float* db = dst + b*NCTRL*2;
    for (int idx = tid; idx < NA*APITCH; idx += 320){
      int r = idx / APITCH;
      int c = idx - r*APITCH;
      float v = 0.0f;
      if (r < NCTRL){
        if (c < NCTRL){
          float dx = sx[r] - sx[c];
          float dy = sy[r] - sy[c];
          v = __builtin_amdgcn_sqrtf(fmaf(dx, dx, dy*dy));
        } else if (c == NCTRL)   v = 1.0f;
        else if (c == NCTRL+1)   v = sx[r];
        else if (c == NCTRL+2)   v = sy[r];
        else if (c == NA)        v = db[2*r];
        else if (c == NA+1)      v = db[2*r+1];
      } else if (c < NCTRL){
        v = (r == NCTRL) ? 1.0f : ((r == NCTRL+1) ? sx[c] : sy[c]);
      }
      Ab[idx] = v;
      if (c < NB) pan[r][c] = v;         // mirror panel-0 columns into LDS
    }
  }
  __syncthreads();

  float rr[NB];
  if (tid < NA){
    #pragma unroll
    for (int q = 0; q < 8; ++q){
      float4 v = *(const float4*)&pan[tid][4*q];
      rr[4*q]=v.x; rr[4*q+1]=v.y; rr[4*q+2]=v.z; rr[4*q+3]=v.w;
    }
  } else {
    #pragma unroll
    for (int c = 0; c < NB; ++c) rr[c] = 0.0f;
  }
  __syncthreads();                        // rr loaded before pan is overwritten

  flat_engine<NB,5>(rr, NA, NB, NB, tid, lane, wid,
                    pan, ftmp, perm, redrow, redv, redi, scanw);

  for (int i = tid; i < NA; i += 320) permbuf[b*(NPAN*NA) + i] = perm[i];
  for (int idx = tid; idx < NA*8; idx += 320){
    int i = idx >> 3, q = idx & 7;
    *(float4*)(Ab + (size_t)i*APITCH + 4*q) = *(const float4*)&pan[i][4*q];
  }
}

// ---------------------------------------------------------------------------
// Kernel 2: trailing update for panel p, one block per 32-col strip.
// laswp gather -> TRSM -> GEMM; strip 0 also factorizes the NEXT panel from
// its LDS strip via the flat engine (ftmp reuses stage; panout reuses pan).
// ---------------------------------------------------------------------------
template<bool LOOK, int NBCN>
__global__ __launch_bounds__(256) void update_kernel(float* __restrict__ A,
                                                     int* __restrict__ permbuf,
                                                     int k0, int pidx, int sb,
                                                     int nbn, int wdn, int wbw){
  const int rows = NA - k0;
  const int ctop = k0 + NB;
  const int tc   = NAUG - ctop;
  const int b    = blockIdx.x / sb;
  const int s    = blockIdx.x - b*sb;
  const int c0   = s*32;
  const int W    = (tc - c0 < 32) ? (tc - c0) : 32;
  float* Ab = A + (size_t)b*NA*APITCH;
  const int tid  = threadIdx.x;
  const int lane = tid & 63;
  const int wid  = tid >> 6;             // 0..3

  __shared__ float pan[NA][PPITCH];      // factored panel; engine output later
  __shared__ float stage[NA][PPITCH];    // permuted strip; engine ftmp later
  __shared__ float ustg[NB][PPITCH];     // U12 strip
  __shared__ int   perm[NA];
  __shared__ float redrow[2][4][PPITCH];
  __shared__ float redv[2][4];
  __shared__ int   redi[2][4], scanw[4];

  for (int i = tid; i < rows; i += 256)
    perm[i] = permbuf[b*(NPAN*NA) + pidx*NA + i];
  for (int idx = tid; idx < rows*8; idx += 256){
    int i = idx >> 3, q = idx & 7;
    *(float4*)&pan[i][4*q] =
      *(const float4*)(Ab + (size_t)(k0+i)*APITCH + k0 + 4*q);
  }
  __syncthreads();

  // laswp gather: stage[i][c] = A[k0+perm[i]][ctop+c0+c]
  for (int idx = tid; idx < rows*W; idx += 256){
    int i = idx / W, c = idx - i*W;
    stage[i][c] = Ab[(size_t)(k0+perm[i])*APITCH + ctop + c0 + c];
  }
  __syncthreads();

  // TRSM: U12 = L11^{-1} A12, thread-per-column from LDS
  if (tid < W){
    float u[NB];
    #pragma unroll
    for (int m = 0; m < NB; ++m) u[m] = stage[m][tid];
    #pragma unroll
    for (int m = 0; m < NB; ++m){
      #pragma unroll
      for (int jj = m+1; jj < NB; ++jj)
        u[jj] = fmaf(-pan[jj][m], u[m], u[jj]);
    }
    #pragma unroll
    for (int m = 0; m < NB; ++m){
      ustg[m][tid] = u[m];
      Ab[(size_t)(k0+m)*APITCH + ctop + c0 + tid] = u[m];
    }
  }
  __syncthreads();

  // GEMM: A22 -= L21 * U12 (4x4 register tiles)
  const int R = rows - NB;
  if (R > 0){
    const int rt = (R + 3) >> 2, ct = (W + 3) >> 2;
    for (int t = tid; t < rt*ct; t += 256){
      int tr = t / ct, tcc = t - tr*ct;
      int i0 = tr*4, cc0 = tcc*4;
      const bool full = (cc0 + 4 <= W);
      int ir[4];
      #pragma unroll
      for (int r = 0; r < 4; ++r){
        int i = i0 + r;
        ir[r] = (i < R) ? i : (R - 1);
      }
      float acc[4][4];
      #pragma unroll
      for (int r = 0; r < 4; ++r){
        if (full){
          float4 v = *(const float4*)&stage[NB + ir[r]][cc0];
          acc[r][0]=v.x; acc[r][1]=v.y; acc[r][2]=v.z; acc[r][3]=v.w;
        } else {
          #pragma unroll
          for (int c = 0; c < 4; ++c)
            acc[r][c] = (cc0 + c < W) ? stage[NB + ir[r]][cc0 + c] : 0.0f;
        }
      }
      #pragma unroll
      for (int mq = 0; mq < NB/4; ++mq){
        float4 lv[4];
        #pragma unroll
        for (int r = 0; r < 4; ++r)
          lv[r] = *(const float4*)&pan[NB + ir[r]][4*mq];
        #pragma unroll
        for (int mi = 0; mi < 4; ++mi){
          float4 uv = *(const float4*)&ustg[4*mq + mi][cc0];
          #pragma unroll
          for (int r = 0; r < 4; ++r){
            float l = (mi==0) ? lv[r].x : (mi==1) ? lv[r].y : (mi==2) ? lv[r].z : lv[r].w;
            acc[r][0] = fmaf(-l, uv.x, acc[r][0]);
            acc[r][1] = fmaf(-l, uv.y, acc[r][1]);
            acc[r][2] = fmaf(-l, uv.z, acc[r][2]);
            acc[r][3] = fmaf(-l, uv.w, acc[r][3]);
          }
        }
      }
      #pragma unroll
      for (int r = 0; r < 4; ++r){
        if (i0 + r < R){
          float* g = Ab + (size_t)(k0 + NB + i0 + r)*APITCH + ctop + c0 + cc0;
          if (full){
            float4 v; v.x=acc[r][0]; v.y=acc[r][1]; v.z=acc[r][2]; v.w=acc[r][3];
            *(float4*)g = v;
            if (LOOK && s == 0) *(float4*)&stage[NB + i0 + r][cc0] = v;
          } else {
            #pragma unroll
            for (int c = 0; c < 4; ++c)
              if (cc0 + c < W){
                g[c] = acc[r][c];
                if (LOOK && s == 0) stage[NB + i0 + r][cc0 + c] = acc[r][c];
              }
          }
        }
      }
    }
  }

  // lookahead: factor the NEXT panel from LDS (strip 0 only)
  if (LOOK && s == 0){
    __syncthreads();
    const int k0n   = k0 + NB;
    const int rowsN = rows - NB;          // <= 227 < 256 threads
    float rr[NBCN];
    if (tid < rowsN){
      #pragma unroll
      for (int q = 0; q < NBCN/4; ++q){
        float4 v = *(const float4*)&stage[NB + tid][4*q];
        rr[4*q]=v.x; rr[4*q+1]=v.y; rr[4*q+2]=v.z; rr[4*q+3]=v.w;
      }
    } else {
      #pragma unroll
      for (int c = 0; c < NBCN; ++c) rr[c] = 0.0f;
    }
    __syncthreads();                      // rr loaded; stage reusable as ftmp

    flat_engine<NBCN,4>(rr, rowsN, nbn, wdn, tid, lane, wid,
                        pan, stage, perm, redrow, redv, redi, scanw);

    for (int i = tid; i < rowsN; i += 256)
      permbuf[b*(NPAN*NA) + (pidx+1)*NA + i] = perm[i];
    if (wbw == NB){
      for (int idx = tid; idx < rowsN*8; idx += 256){
        int i = idx >> 3, q = idx & 7;
        *(float4*)(Ab + (size_t)(k0n+i)*APITCH + k0n + 4*q) =
          *(const float4*)&pan[i][4*q];
      }
    } else {
      for (int idx = tid; idx < rowsN*wbw; idx += 256){
        int i = idx / wbw, c = idx - i*wbw;
        Ab[(size_t)(k0n+i)*APITCH + k0n + c] = pan[i][c];
      }
    }
  }
}

// ---------------------------------------------------------------------------
// Kernel 3: back-substitution (r7-proven right-looking version).
// ---------------------------------------------------------------------------
__global__ __launch_bounds__(512) void backsub_kernel(const float* __restrict__ A,
                                                      float* __restrict__ wv){
  const int b = blockIdx.x;
  const float* Ab = A + (size_t)b*NA*APITCH;
  const int tid  = threadIdx.x;
  const int lane = tid & 63;
  const int wid  = tid >> 6;

  __shared__ float t2[NA][2];
  __shared__ float xs[NA][2];
  __shared__ float u11[NB][NB+1];

  for (int i = tid; i < NA; i += 512){
    t2[i][0] = Ab[(size_t)i*APITCH + NA];
    t2[i][1] = Ab[(size_t)i*APITCH + NA + 1];
  }
  __syncthreads();

  for (int bp = NPAN-1; bp >= 0; --bp){
    const int k0 = bp*NB;
    const int nb = (NA - k0 < NB) ? (NA - k0) : NB;

    for (int idx = tid; idx < nb*nb; idx += 512){
      int r = idx / nb, c = idx - r*nb;
      u11[r][c] = Ab[(size_t)(k0+r)*APITCH + k0 + c];
    }
    __syncthreads();

    if (wid == 0){
      int j = lane >> 1, ch = lane & 1;
      float tval = (j < nb) ? t2[k0+j][ch] : 0.0f;
      for (int k = nb-1; k >= 0; --k){
        float tk = __shfl(tval, 2*k + ch);
        float xk = tk / u11[k][k];
        if (j <  k) tval = fmaf(-u11[j][k], xk, tval);
        if (j == k) tval = xk;
      }
      if (j < nb) xs[k0+j][ch] = tval;
    }
    __syncthreads();

    if (nb == NB){
      const int q = tid & 7;
      for (int base = 0; base < k0; base += 64){
        const int i = base + (tid >> 3);
        float px = 0.0f, py = 0.0f;
        if (i < k0){
          float4 v = *(const float4*)(Ab + (size_t)i*APITCH + k0 + 4*q);
          px = v.x*xs[k0+4*q+0][0] + v.y*xs[k0+4*q+1][0]
             + v.z*xs[k0+4*q+2][0] + v.w*xs[k0+4*q+3][0];
          py = v.x*xs[k0+4*q+0][1] + v.y*xs[k0+4*q+1][1]
             + v.z*xs[k0+4*q+2][1] + v.w*xs[k0+4*q+3][1];
        }
        px += __shfl_xor(px, 1); px += __shfl_xor(px, 2); px += __shfl_xor(px, 4);
        py += __shfl_xor(py, 1); py += __shfl_xor(py, 2); py += __shfl_xor(py, 4);
        if (q == 0 && i < k0){
          t2[i][0] -= px;
          t2[i][1] -= py;
        }
      }
    } else {
      for (int i = tid; i < k0; i += 512){
        float s0 = 0.0f, s1 = 0.0f;
        #pragma unroll
        for (int m = 0; m < 3; ++m){
          float u = Ab[(size_t)i*APITCH + k0 + m];
          s0 = fmaf(u, xs[k0+m][0], s0);
          s1 = fmaf(u, xs[k0+m][1], s1);
        }
        t2[i][0] -= s0;
        t2[i][1] -= s1;
      }
    }
    __syncthreads();
  }

  for (int i = tid; i < NA; i += 512){
    wv[((size_t)b*NA + i)*2 + 0] = xs[i][0];
    wv[((size_t)b*NA + i)*2 + 1] = xs[i][1];
  }
}

// ---------------------------------------------------------------------------
// Kernel 4: evaluate the warp (r10-proven: PY=4, v_sqrt_f32, float4 LDS).
// ---------------------------------------------------------------------------
__global__ __launch_bounds__(256) void eval_kernel(const float* __restrict__ src,
                                                   const float* __restrict__ wv,
                                                   float* __restrict__ out){
  const int b  = blockIdx.x >> 6;          // 8 batches x 64 y-groups
  const int yg = blockIdx.x & 63;
  const int xi = threadIdx.x;
  __shared__ float4 cw[NCTRL];             // (sx, sy, wx, wy)
  const float* sb = src + b*NCTRL*2;
  const float* wb = wv + (size_t)b*NA*2;
  {
    float2 sv = ((const float2*)sb)[xi];
    float2 wv2 = ((const float2*)wb)[xi];
    cw[xi] = make_float4(sv.x, sv.y, wv2.x, wv2.y);
  }
  __syncthreads();

  const float step = 2.0f/255.0f;
  const float gx = -1.0f + step*(float)xi;
  const float w0x = wb[512], w1x = wb[514], w2x = wb[516];
  const float w0y = wb[513], w1y = wb[515], w2y = wb[517];

  float gy[PY], ax[PY], ay[PY];
  #pragma unroll
  for (int p = 0; p < PY; ++p){
    gy[p] = -1.0f + step*(float)(yg*PY + p);
    ax[p] = w0x + w1x*gx + w2x*gy[p];
    ay[p] = w0y + w1y*gx + w2y*gy[p];
  }

  #pragma unroll 4
  for (int j = 0; j < NCTRL; ++j){
    float4 c = cw[j];
    float dx = gx - c.x;
    float dx2 = dx*dx;
    #pragma unroll
    for (int p = 0; p < PY; ++p){
      float dy = gy[p] - c.y;
      float r = __builtin_amdgcn_sqrtf(fmaf(dy, dy, dx2));
      ax[p] = fmaf(r, c.z, ax[p]);
      ay[p] = fmaf(r, c.w, ay[p]);
    }
  }

  const int y0 = yg*PY;
  #pragma unroll
  for (int p = 0; p < PY; ++p){
    out[((size_t)(b*2    )*SGRID + y0 + p)*SGRID + xi] = ax[p];
    out[((size_t)(b*2 + 1)*SGRID + y0 + p)*SGRID + xi] = ay[p];
  }
}

// ---------------------------------------------------------------------------
extern "C" void kernel_launch(void* const* d_in, const int* in_sizes, int n_in,
                              void* d_out, int out_size, void* d_ws, size_t ws_size,
                              hipStream_t stream) {
  const float* src = (const float*)d_in[0];
  const float* dst = (const float*)d_in[1];
  float* out = (float*)d_out;

  const size_t matElems = (size_t)BATCH*NA*APITCH;
  float* A     = (float*)d_ws;
  float* wv    = A + matElems;
  int*   permb = (int*)(wv + (size_t)BATCH*NA*2);

  // build + panel 0
  build_panel0<<<BATCH, 320, 0, stream>>>(src, dst, A, permb);

  // p = 0..6: update + lookahead of panel p+1 (width 32)
  for (int p = 0; p <= 6; ++p){
    const int k0 = p*NB;
    const int tc = NAUG - (k0 + NB);
    const int sb = (tc + 31) >> 5;
    update_kernel<true, NB><<<BATCH*sb, 256, 0, stream>>>(A, permb, k0, p, sb,
                                                          NB, NB, NB);
  }
  // p = 7: update (1 strip) + lookahead of the 5-wide tail block
  // (3 panel cols + 2 rhs; engine eliminates rhs via its shift updates)
  update_kernel<true, 8><<<BATCH, 256, 0, stream>>>(A, permb, 7*NB, 7, 1,
                                                    3, 5, 5);

  backsub_kernel<<<BATCH, 512, 0, stream>>>(A, wv);
  eval_kernel<<<BATCH*(SGRID/PY), 256, 0, stream>>>(src, wv, out);
}